// Round 10
// baseline (212.336 us; speedup 1.0000x reference)
//
#include <hip/hip_runtime.h>

#define SEQ 2048
#define DMODEL 1024
#define HEADS 16
#define DH 64
// fold (1/sqrt(64)) * log2(e) into Wq so scores arrive in exp2 domain
#define QSCALE 0.180336880f

typedef __attribute__((ext_vector_type(8))) short short8;
typedef __attribute__((ext_vector_type(4))) float f32x4;
typedef _Float16 half8 __attribute__((ext_vector_type(8)));
typedef __fp16 fp16x2 __attribute__((ext_vector_type(2)));

__device__ __forceinline__ ushort f2bf(float x) {
  union { float f; unsigned u; } v; v.f = x;
  return (ushort)((v.u + 0x7fffu + ((v.u >> 16) & 1u)) >> 16);
}

// pack 2 fp32 -> 2 fp16 (RTZ), as ushort2 bits
__device__ __forceinline__ ushort2 pk16(float x, float y) {
  union { fp16x2 h; ushort2 u; } v;
  v.h = __builtin_amdgcn_cvt_pkrtz(x, y);
  return v.u;
}

// async global->LDS, 16B per lane. LDS dest = wave-uniform base + lane*16.
__device__ __forceinline__ void gld16(const ushort* g, ushort* l) {
  __builtin_amdgcn_global_load_lds(
      (const __attribute__((address_space(1))) unsigned int*)g,
      (__attribute__((address_space(3))) unsigned int*)l, 16, 0, 0);
}

// fragment-major index for Q/K [bh][s>>4][d>>5][lane q*16+ln][j=d&7]
__device__ __forceinline__ size_t qk_idx(int bh, int s, int d) {
  return ((((size_t)bh * (SEQ / 16) + (s >> 4)) * 2 + (d >> 5)) * 64 +
          ((d >> 3) & 3) * 16 + (s & 15)) * 8 + (d & 7);
}
// fragment-major index for V^T [bh][d>>4][s>>5][lane][j=s&7]
__device__ __forceinline__ size_t v_idx(int bh, int s, int d) {
  return ((((size_t)bh * 4 + (d >> 4)) * (SEQ / 32) + (s >> 5)) * 64 +
          ((s >> 3) & 3) * 16 + (d & 15)) * 8 + (s & 7);
}

// ---------------------------------------------------------------------------
// Fused prologue. z=0/1: fp32->bf16 cast of patch/pixel (4x float4/thread).
// z=2..5: transpose-cast Wq*QSCALE / Wk / Wv / Wo to [N][K] bf16.
// ---------------------------------------------------------------------------
__global__ __launch_bounds__(256) void prologue(
    const float* __restrict__ patch, const float* __restrict__ pixel,
    const float* __restrict__ W0, const float* __restrict__ W1,
    const float* __restrict__ W2, const float* __restrict__ W3,
    ushort* __restrict__ pb, ushort* __restrict__ xb,
    ushort* __restrict__ O0, ushort* __restrict__ O1,
    ushort* __restrict__ O2, ushort* __restrict__ O3) {
  const int z = blockIdx.z;
  const int tx = threadIdx.x, ty = threadIdx.y;
  if (z < 2) {
    const float4* in = (const float4*)(z ? pixel : patch);
    ushort4* out = (ushort4*)(z ? xb : pb);
    const int base = (blockIdx.y * 32 + blockIdx.x) * 256 + ty * 32 + tx;
#pragma unroll
    for (int rep = 0; rep < 4; ++rep) {
      const int i = base + rep * 262144;
      float4 f = in[i];
      out[i] = make_ushort4(f2bf(f.x), f2bf(f.y), f2bf(f.z), f2bf(f.w));
    }
    return;
  }
  __shared__ float tile[32][33];
  const int zz = z - 2;
  const float* in = zz == 0 ? W0 : zz == 1 ? W1 : zz == 2 ? W2 : W3;
  ushort* out = zz == 0 ? O0 : zz == 1 ? O1 : zz == 2 ? O2 : O3;
  const float scale = zz == 0 ? QSCALE : 1.0f;
  const int n0 = blockIdx.x * 32, k0 = blockIdx.y * 32;
#pragma unroll
  for (int i = 0; i < 4; ++i)
    tile[ty + i * 8][tx] = in[(size_t)(k0 + ty + i * 8) * DMODEL + n0 + tx];
  __syncthreads();
#pragma unroll
  for (int i = 0; i < 4; ++i)
    out[(size_t)(n0 + ty + i * 8) * DMODEL + k0 + tx] =
        f2bf(tile[tx][ty + i * 8] * scale);
}

// ---------------------------------------------------------------------------
// Fused Q/K/V projection GEMM, global_load_lds(16B) staging, XOR-swizzled on
// the GLOBAL side. 128x128 tile, BK=64, 4 waves. Epilogues scatter to the
// fragment-major layouts consumed by flash_mfma. V is cast to FP16 (pkrtz).
// ---------------------------------------------------------------------------
__global__ __launch_bounds__(256) void mfma_gemm_qkv(
    const ushort* __restrict__ pb, const ushort* __restrict__ xb,
    const ushort* __restrict__ wqt, const ushort* __restrict__ wkt,
    const ushort* __restrict__ wvt, ushort* __restrict__ qws,
    ushort* __restrict__ kws, ushort* __restrict__ vws) {
  __shared__ __align__(16) ushort As[128 * 64];
  __shared__ __align__(16) ushort Bs[128 * 64];
  const int z = blockIdx.z;
  const ushort* A = (z == 0) ? pb : xb;
  const ushort* Bt = (z == 0) ? wqt : (z == 1) ? wkt : wvt;

  const int t = threadIdx.x;
  const int w = t >> 6, lane = t & 63, ln = lane & 15, q = lane >> 4;
  const int wm = w & 1, wn = w >> 1;
  const int row0 = blockIdx.y * 128, col0 = blockIdx.x * 128;
  const int sw = ln & 7;

  f32x4 acc[4][4];
#pragma unroll
  for (int i = 0; i < 4; ++i)
#pragma unroll
    for (int j = 0; j < 4; ++j) acc[i][j] = (f32x4){0.f, 0.f, 0.f, 0.f};

  for (int k0 = 0; k0 < DMODEL; k0 += 64) {
    __syncthreads();  // prior frag reads done
#pragma unroll
    for (int rep = 0; rep < 4; ++rep) {
      const int u0 = rep * 256 + w * 64;
      const int u = u0 + lane;
      const int r = u >> 3, gl = (u & 7) ^ (r & 7);
      gld16(&A[(size_t)(row0 + r) * DMODEL + k0 + gl * 8], &As[u0 * 8]);
      gld16(&Bt[(size_t)(col0 + r) * DMODEL + k0 + gl * 8], &Bs[u0 * 8]);
    }
    __syncthreads();  // vmcnt drain
#pragma unroll
    for (int ks = 0; ks < 2; ++ks) {
      short8 af[4], bf[4];
#pragma unroll
      for (int rt = 0; rt < 4; ++rt)
        af[rt] = *(const short8*)&As[(wm * 64 + rt * 16 + ln) * 64 +
                                     (((ks * 4 + q) ^ sw) * 8)];
#pragma unroll
      for (int ct = 0; ct < 4; ++ct)
        bf[ct] = *(const short8*)&Bs[(wn * 64 + ct * 16 + ln) * 64 +
                                     (((ks * 4 + q) ^ sw) * 8)];
#pragma unroll
      for (int rt = 0; rt < 4; ++rt)
#pragma unroll
        for (int ct = 0; ct < 4; ++ct)
          acc[rt][ct] = __builtin_amdgcn_mfma_f32_16x16x32_bf16(af[rt], bf[ct],
                                                                acc[rt][ct], 0, 0, 0);
    }
  }

  if (z < 2) {
    ushort* dst = z == 0 ? qws : kws;
#pragma unroll
    for (int rt = 0; rt < 4; ++rt)
#pragma unroll
      for (int ct = 0; ct < 4; ++ct) {
        const int c = col0 + wn * 64 + ct * 16 + ln;
        const int h = c >> 6, d = c & 63;
#pragma unroll
        for (int reg = 0; reg < 4; ++reg) {
          const int r = row0 + wm * 64 + rt * 16 + q * 4 + reg;
          const int b = r >> 11, s = r & (SEQ - 1);
          dst[qk_idx(b * HEADS + h, s, d)] = f2bf(acc[rt][ct][reg]);
        }
      }
  } else {
#pragma unroll
    for (int rt = 0; rt < 4; ++rt)
#pragma unroll
      for (int ct = 0; ct < 4; ++ct) {
        const int c = col0 + wn * 64 + ct * 16 + ln;
        const int h = c >> 6, d = c & 63;
        const int r0 = row0 + wm * 64 + rt * 16 + q * 4;
        const int b = r0 >> 11, s0 = r0 & (SEQ - 1);
        const ushort2 p01 = pk16(acc[rt][ct][0], acc[rt][ct][1]);
        const ushort2 p23 = pk16(acc[rt][ct][2], acc[rt][ct][3]);
        *(ushort4*)&vws[v_idx(b * HEADS + h, s0, d)] =
            make_ushort4(p01.x, p01.y, p23.x, p23.y);
      }
  }
}

// ---------------------------------------------------------------------------
// Flash attention v5: Q-tile 128 (4 waves, 32 rows/wave), double-buffered
// unified K/V staging (hoisted pointer arithmetic), single barrier per iter.
// P and V in FP16 (pkrtz pack = 1 VALU per 2 values; 16x16x32_f16 PV MFMA).
// Grid (x=bh 32, y=qt 16) = 512 blocks; x=bh pins bh to an XCD for K/V L2
// residency. LDS 50 KB.
// ---------------------------------------------------------------------------
__global__ __launch_bounds__(256, 2) void flash_mfma(
    const ushort* __restrict__ Qg, const ushort* __restrict__ Kg,
    const ushort* __restrict__ Vg, ushort* __restrict__ Og) {
  __shared__ __align__(16) ushort KVst[2][16 * 512];  // 2 x 16 KB (K:0-7,V:8-15)
  __shared__ __align__(16) ushort Ps[128 * 72];       // 18 KB, wave-private rows

  const int t = threadIdx.x;
  const int w = t >> 6, lane = t & 63, ln = lane & 15, q = lane >> 4;
  const int bh = blockIdx.x;   // 0..31  (XCD-pinning: id%8 = bh%8)
  const int qt = blockIdx.y;   // 0..15  (128-row Q tile)

  const ushort* qg = Qg + (size_t)bh * SEQ * DH;
  const ushort* kg = Kg + (size_t)bh * SEQ * DH;
  const ushort* vg = Vg + (size_t)bh * DH * SEQ;

  // hoisted staging pointers: wave w owns frags w*4..w*4+3 (K: f<8, V: f>=8)
  const ushort* sp[4];
  int sstride[4];
  ushort* ld0[4];
  ushort* ld1[4];
#pragma unroll
  for (int i = 0; i < 4; ++i) {
    const int f = w * 4 + i;
    if (f < 8) {
      sp[i] = kg + (size_t)f * 512 + lane * 8;
      sstride[i] = 8 * 512;  // advance one K-tile (8 frags) per kt
    } else {
      const int f2 = f - 8, nt = f2 >> 1, ks2 = f2 & 1;
      sp[i] = vg + ((size_t)nt * (SEQ / 32) + ks2) * 512 + lane * 8;
      sstride[i] = 2 * 512;  // advance 2 s-groups per kt
    }
    ld0[i] = &KVst[0][f * 512];
    ld1[i] = &KVst[1][f * 512];
  }

  // Q A-fragments (2 row-tiles x 2 k-halves), coalesced lane*16B loads
  short8 qf[2][2];
#pragma unroll
  for (int rt = 0; rt < 2; ++rt)
#pragma unroll
    for (int ks = 0; ks < 2; ++ks)
      qf[rt][ks] = *(const short8*)
          &qg[(((size_t)(qt * 8 + w * 2 + rt) * 2 + ks) * 64 + lane) * 8];

  float l_i[2][4];
  f32x4 acc_o[2][4];
#pragma unroll
  for (int rt = 0; rt < 2; ++rt)
#pragma unroll
    for (int reg = 0; reg < 4; ++reg) l_i[rt][reg] = 0.f;
#pragma unroll
  for (int rt = 0; rt < 2; ++rt)
#pragma unroll
    for (int nt = 0; nt < 4; ++nt) acc_o[rt][nt] = (f32x4){0.f, 0.f, 0.f, 0.f};

  // stage kt=0 into buffer 0
#pragma unroll
  for (int i = 0; i < 4; ++i) {
    gld16(sp[i], ld0[i]);
    sp[i] += sstride[i];
  }
  __syncthreads();

  const int prow = w * 32;  // wave's first P row

  for (int kt = 0; kt < SEQ / 64; ++kt) {
    const int cur = kt & 1;
    const ushort* KV = KVst[cur];
    // issue NEXT iter's DMA first (lands during this iter's compute)
    if (kt + 1 < SEQ / 64) {
#pragma unroll
      for (int i = 0; i < 4; ++i) {
        gld16(sp[i], cur ? ld0[i] : ld1[i]);
        sp[i] += sstride[i];
      }
    }

    // S = Q @ K^T (wave: 32 x 64), bf16 MFMA
    f32x4 accs[2][4];
#pragma unroll
    for (int rt = 0; rt < 2; ++rt)
#pragma unroll
      for (int ct = 0; ct < 4; ++ct) accs[rt][ct] = (f32x4){0.f, 0.f, 0.f, 0.f};
#pragma unroll
    for (int ks = 0; ks < 2; ++ks)
#pragma unroll
      for (int ct = 0; ct < 4; ++ct) {
        const short8 bf = *(const short8*)&KV[(ct * 2 + ks) * 512 + lane * 8];
#pragma unroll
        for (int rt = 0; rt < 2; ++rt)
          accs[rt][ct] = __builtin_amdgcn_mfma_f32_16x16x32_bf16(
              qf[rt][ks], bf, accs[rt][ct], 0, 0, 0);
      }

    // p = 2^s (Q pre-scaled), lane-partial l, P -> fp16 pairs in LDS
#pragma unroll
    for (int rt = 0; rt < 2; ++rt)
#pragma unroll
      for (int ct = 0; ct < 4; ++ct) {
        float p[4];
#pragma unroll
        for (int reg = 0; reg < 4; ++reg) {
          p[reg] = __builtin_amdgcn_exp2f(accs[rt][ct][reg]);
          l_i[rt][reg] += p[reg];
        }
        const int col = ct * 16 + ln;
        const int r0 = prow + rt * 16 + q * 4;
        const ushort2 p01 = pk16(p[0], p[1]);
        const ushort2 p23 = pk16(p[2], p[3]);
        Ps[(r0 + 0) * 72 + col] = p01.x;
        Ps[(r0 + 1) * 72 + col] = p01.y;
        Ps[(r0 + 2) * 72 + col] = p23.x;
        Ps[(r0 + 3) * 72 + col] = p23.y;
      }

    // O += P @ V, fp16 MFMA (V staged as fp16)
#pragma unroll
    for (int ks2 = 0; ks2 < 2; ++ks2) {
      half8 pa[2];
#pragma unroll
      for (int rt = 0; rt < 2; ++rt)
        pa[rt] = *(const half8*)&Ps[(prow + rt * 16 + ln) * 72 + ks2 * 32 + q * 8];
#pragma unroll
      for (int nt = 0; nt < 4; ++nt) {
        const half8 bv = *(const half8*)&KV[(8 + nt * 2 + ks2) * 512 + lane * 8];
#pragma unroll
        for (int rt = 0; rt < 2; ++rt)
          acc_o[rt][nt] = __builtin_amdgcn_mfma_f32_16x16x32_f16(
              pa[rt], bv, acc_o[rt][nt], 0, 0, 0);
      }
    }

    __syncthreads();  // single barrier: next DMA drained + buffers swappable
  }

  // epilogue: reduce l over the quad's 16 lanes, normalize, write aws bf16
  const int b = bh >> 4, h = bh & 15;
#pragma unroll
  for (int rt = 0; rt < 2; ++rt)
#pragma unroll
    for (int reg = 0; reg < 4; ++reg) {
      float l = l_i[rt][reg];
      l += __shfl_xor(l, 1, 16);
      l += __shfl_xor(l, 2, 16);
      l += __shfl_xor(l, 4, 16);
      l += __shfl_xor(l, 8, 16);
      const float inv = 1.0f / l;
      const int s = qt * 128 + w * 32 + rt * 16 + q * 4 + reg;
#pragma unroll
      for (int nt = 0; nt < 4; ++nt)
        Og[(size_t)(b * SEQ + s) * DMODEL + h * DH + nt * 16 + ln] =
            f2bf(acc_o[rt][nt][reg] * inv);
    }
}

// ---------------------------------------------------------------------------
// Output projection: out = aws[4096,1024] @ WoT^T + bo (fp32). 64x128 tile,
// BK=64, global_load_lds staging, 512 blocks.
// ---------------------------------------------------------------------------
__global__ __launch_bounds__(256) void mfma_gemm_out(const ushort* __restrict__ A,
                                                     const ushort* __restrict__ Bt,
                                                     const float* __restrict__ bias,
                                                     float* __restrict__ dst) {
  __shared__ __align__(16) ushort As[64 * 64];
  __shared__ __align__(16) ushort Bs[128 * 64];
  const int t = threadIdx.x;
  const int w = t >> 6, lane = t & 63, ln = lane & 15, q = lane >> 4;
  const int wm = w & 1, wn = w >> 1;
  const int row0 = blockIdx.y * 64, col0 = blockIdx.x * 128;
  const int sw = ln & 7;

  f32x4 acc[2][4];
#pragma unroll
  for (int i = 0; i < 2; ++i)
#pragma unroll
    for (int j = 0; j < 4; ++j) acc[i][j] = (f32x4){0.f, 0.f, 0.f, 0.f};

  for (int k0 = 0; k0 < DMODEL; k0 += 64) {
    __syncthreads();
#pragma unroll
    for (int rep = 0; rep < 2; ++rep) {
      const int u0 = rep * 256 + w * 64;
      const int u = u0 + lane;
      const int r = u >> 3, gl = (u & 7) ^ (r & 7);
      gld16(&A[(size_t)(row0 + r) * DMODEL + k0 + gl * 8], &As[u0 * 8]);
    }
#pragma unroll
    for (int rep = 0; rep < 4; ++rep) {
      const int u0 = rep * 256 + w * 64;
      const int u = u0 + lane;
      const int r = u >> 3, gl = (u & 7) ^ (r & 7);
      gld16(&Bt[(size_t)(col0 + r) * DMODEL + k0 + gl * 8], &Bs[u0 * 8]);
    }
    __syncthreads();
#pragma unroll
    for (int ks = 0; ks < 2; ++ks) {
      short8 af[2], bf[4];
#pragma unroll
      for (int rt = 0; rt < 2; ++rt)
        af[rt] = *(const short8*)&As[(wm * 32 + rt * 16 + ln) * 64 +
                                     (((ks * 4 + q) ^ sw) * 8)];
#pragma unroll
      for (int ct = 0; ct < 4; ++ct)
        bf[ct] = *(const short8*)&Bs[(wn * 64 + ct * 16 + ln) * 64 +
                                     (((ks * 4 + q) ^ sw) * 8)];
#pragma unroll
      for (int rt = 0; rt < 2; ++rt)
#pragma unroll
        for (int ct = 0; ct < 4; ++ct)
          acc[rt][ct] = __builtin_amdgcn_mfma_f32_16x16x32_bf16(af[rt], bf[ct],
                                                                acc[rt][ct], 0, 0, 0);
    }
  }

#pragma unroll
  for (int rt = 0; rt < 2; ++rt)
#pragma unroll
    for (int ct = 0; ct < 4; ++ct) {
      const int c = col0 + wn * 64 + ct * 16 + ln;
      const float bi = bias[c];
#pragma unroll
      for (int reg = 0; reg < 4; ++reg) {
        const int r = row0 + wm * 32 + rt * 16 + q * 4 + reg;
        dst[(size_t)r * DMODEL + c] = acc[rt][ct][reg] + bi;
      }
    }
}

extern "C" void kernel_launch(void* const* d_in, const int* in_sizes, int n_in,
                              void* d_out, int out_size, void* d_ws,
                              size_t ws_size, hipStream_t stream) {
  const float* patch = (const float*)d_in[0];
  const float* pixel = (const float*)d_in[1];
  const float* Wq = (const float*)d_in[2];
  const float* Wk = (const float*)d_in[3];
  const float* Wv = (const float*)d_in[4];
  const float* Wo = (const float*)d_in[5];
  const float* bo = (const float*)d_in[6];
  float* out = (float*)d_out;

  const size_t E = (size_t)2 * SEQ * DMODEL;  // 4,194,304
  const size_t W = (size_t)DMODEL * DMODEL;   // 1,048,576
  ushort* pb  = (ushort*)d_ws;      // patch bf16
  ushort* xb  = pb + E;             // pixel bf16
  ushort* wqt = xb + E;             // Wq^T * QSCALE bf16 [N][K]
  ushort* wkt = wqt + W;
  ushort* wvt = wkt + W;
  ushort* wot = wvt + W;            // live until mfma_gemm_out
  ushort* qws = wot + W;            // Q fragment-major (bf16)
  ushort* kws = qws + E;            // K fragment-major (bf16)
  ushort* vws = kws + E;            // V^T fragment-major (FP16)
  ushort* aws = vws + E;            // [4096][1024] row-major bf16

  prologue<<<dim3(32, 32, 6), dim3(32, 8), 0, stream>>>(
      patch, pixel, Wq, Wk, Wv, Wo, pb, xb, wqt, wkt, wvt, wot);
  mfma_gemm_qkv<<<dim3(8, 32, 3), 256, 0, stream>>>(pb, xb, wqt, wkt, wvt,
                                                    qws, kws, vws);
  flash_mfma<<<dim3(32, 16), 256, 0, stream>>>(qws, kws, vws, aws);
  mfma_gemm_out<<<dim3(8, 64), 256, 0, stream>>>(aws, wot, bo, out);
}